// Round 1
// baseline (117.414 us; speedup 1.0000x reference)
//
#include <hip/hip_runtime.h>

#define BATCH 16384
#define DIM   512
#define UNITS 1024
// GAMMA = 0.5 folded: out = exp(cross - 0.5*xsq - 0.5*musq)

typedef float v16f __attribute__((ext_vector_type(16)));

#define MFMA(a, b, c) __builtin_amdgcn_mfma_f32_32x32x16_fp8_fp8((a), (b), (c), 0, 0, 0)

// Single fused kernel, 256 blocks x 1024 threads (16 waves, 1 block/CU).
// Block tile 256M x 256N. Grid map: b&7 = XCD, mt = xcd*8 + (j&7), nt = j>>3
// so the 4 blocks sharing an A m-tile sit on the same XCD (L2-local A reads).
//
// Phase B: all 16 waves convert this block's mu columns (fp32, L2-resident)
//   into fragment-order fp8 in LDS (Bs, 128 KB) + musq partials.
//   Fragment: byte ((ng*32+kw)*64+l)*8 holds B[kw*16+(l>>5)*8+j][n0+ng*32+(l&31)].
// Phase A-loop (16 chunks of 32 k-cols): stage thread t owns row t>>2,
//   8-float part t&3: coalesced float4 pair -> xsq fmacs -> cvt_pk fp8 ->
//   ds_write_b64 into fragment-order As dbuf (2 x 8 KB). One barrier/chunk;
//   chunk i+1 global loads issued before chunk i's MFMAs (latency hidden).
// Epilogue: C/D layout col=l&31, row=(r&3)+8*(r>>2)+4*(l>>5); exp + NT store.
__global__ __launch_bounds__(1024, 4)
void rbf_fused_kernel(const float* __restrict__ in, const float* __restrict__ mu,
                      float* __restrict__ out) {
    __shared__ __attribute__((aligned(16))) unsigned char smem[155648];
    unsigned char* Bs = smem;                       // [8 ng][32 kw][64 l][8] fp8
    unsigned char* As = smem + 131072;              // 2 x [8 rg][2 kwh][64 l][8] fp8
    float* xsq_red  = (float*)(smem + 147456);      // [256][4]
    float* musq_red = (float*)(smem + 151552);      // [256][2]
    float* xsq_l    = (float*)(smem + 153600);      // [256]
    float* musq_l   = (float*)(smem + 154624);      // [256]

    const int t  = threadIdx.x;
    const int l  = t & 63;
    const int w  = t >> 6;          // wave 0..15
    const int ln = l & 31;
    const int h  = l >> 5;

    const int b   = blockIdx.x;     // 0..255
    const int xcd = b & 7;
    const int j   = b >> 3;
    const int m0  = (xcd * 8 + (j & 7)) * 256;
    const int n0  = (j >> 3) * 256;
    const int wm  = (w >> 2) * 64;
    const int wn  = (w & 3) * 64;

    // ---- A staging role: thread t owns local row ar, 8-float part ap ----
    const int ar = t >> 2, ap = t & 3;
    const float* arow = in + (size_t)(m0 + ar) * DIM + ap * 8;
    // dest (bytes) in As buffer: frag (kwh=ap>>1), lane (ap&1)*32+(ar&31), rg=ar>>5
    const int aidx = ((((ar >> 5) * 2 + (ap >> 1)) * 64) + (ap & 1) * 32 + (ar & 31)) * 8;

    // Issue chunk-0 A loads early; their latency hides under phase B.
    float4 g0 = *(const float4*)(arow + 0);
    float4 g1 = *(const float4*)(arow + 4);

    // ---- Phase B: mu -> fp8 fragments in LDS + musq ----
    {
        const int ng  = w >> 1;             // 0..7 column group
        const int kwb = (w & 1) * 16;       // k-half
        const float* msrc = mu + (size_t)(kwb * 16 + h * 8) * UNITS + n0 + ng * 32 + ln;
        unsigned char* bdst = Bs + ((ng * 32 + kwb) * 64 + l) * 8;
        float s = 0.f;
#pragma unroll 4
        for (int kk = 0; kk < 16; kk++) {
            float v[8];
#pragma unroll
            for (int jj = 0; jj < 8; jj++) v[jj] = msrc[(size_t)(kk * 16 + jj) * UNITS];
#pragma unroll
            for (int jj = 0; jj < 8; jj++) s += v[jj] * v[jj];
            int lo = __builtin_amdgcn_cvt_pk_fp8_f32(v[0], v[1], 0, false);
            lo     = __builtin_amdgcn_cvt_pk_fp8_f32(v[2], v[3], lo, true);
            int hi = __builtin_amdgcn_cvt_pk_fp8_f32(v[4], v[5], 0, false);
            hi     = __builtin_amdgcn_cvt_pk_fp8_f32(v[6], v[7], hi, true);
            *(int2*)(bdst + kk * 512) = make_int2(lo, hi);
        }
        s += __shfl_xor(s, 32, 64);         // combine h halves per column
        if (h == 0) musq_red[(ng * 32 + ln) * 2 + (w & 1)] = s;
    }

    // chunk-0 xsq + convert + stage into As buf 0
    float sA = g0.x * g0.x + g0.y * g0.y + g0.z * g0.z + g0.w * g0.w
             + g1.x * g1.x + g1.y * g1.y + g1.z * g1.z + g1.w * g1.w;
    {
        int lo = __builtin_amdgcn_cvt_pk_fp8_f32(g0.x, g0.y, 0, false);
        lo     = __builtin_amdgcn_cvt_pk_fp8_f32(g0.z, g0.w, lo, true);
        int hi = __builtin_amdgcn_cvt_pk_fp8_f32(g1.x, g1.y, 0, false);
        hi     = __builtin_amdgcn_cvt_pk_fp8_f32(g1.z, g1.w, hi, true);
        *(int2*)(As + aidx) = make_int2(lo, hi);
    }
    __syncthreads();
    if (t < 256) musq_l[t] = -0.5f * (musq_red[t * 2] + musq_red[t * 2 + 1]);

    // ---- Main loop: 16 chunks x (2 kw x 4 MFMA), dbuf, 1 barrier/chunk ----
    const long* BsL = (const long*)Bs;
    v16f acc[2][2];
#pragma unroll
    for (int c = 0; c < 2; c++)
#pragma unroll
        for (int g = 0; g < 2; g++) acc[c][g] = (v16f)0.f;

#pragma unroll 2
    for (int i = 0; i < 16; i++) {
        float4 f0, f1;
        if (i < 15) {                        // issue next-chunk loads first
            f0 = *(const float4*)(arow + (i + 1) * 32);
            f1 = *(const float4*)(arow + (i + 1) * 32 + 4);
        }
        const long* AsL = (const long*)(As + (i & 1) * 8192);
        long a[2][2], bb[2][2];
#pragma unroll
        for (int c = 0; c < 2; c++)
#pragma unroll
            for (int kh = 0; kh < 2; kh++)
                a[c][kh] = AsL[(((w >> 2) * 2 + c) * 2 + kh) * 64 + l];
#pragma unroll
        for (int g = 0; g < 2; g++)
#pragma unroll
            for (int kh = 0; kh < 2; kh++)
                bb[g][kh] = BsL[(((w & 3) * 2 + g) * 32 + 2 * i + kh) * 64 + l];
#pragma unroll
        for (int kh = 0; kh < 2; kh++) {
            acc[0][0] = MFMA(a[0][kh], bb[0][kh], acc[0][0]);
            acc[0][1] = MFMA(a[0][kh], bb[1][kh], acc[0][1]);
            acc[1][0] = MFMA(a[1][kh], bb[0][kh], acc[1][0]);
            acc[1][1] = MFMA(a[1][kh], bb[1][kh], acc[1][1]);
        }
        if (i < 15) {                        // convert+stage into other buffer
            sA += f0.x * f0.x + f0.y * f0.y + f0.z * f0.z + f0.w * f0.w
                + f1.x * f1.x + f1.y * f1.y + f1.z * f1.z + f1.w * f1.w;
            int lo = __builtin_amdgcn_cvt_pk_fp8_f32(f0.x, f0.y, 0, false);
            lo     = __builtin_amdgcn_cvt_pk_fp8_f32(f0.z, f0.w, lo, true);
            int hi = __builtin_amdgcn_cvt_pk_fp8_f32(f1.x, f1.y, 0, false);
            hi     = __builtin_amdgcn_cvt_pk_fp8_f32(f1.z, f1.w, hi, true);
            *(int2*)(As + ((i + 1) & 1) * 8192 + aidx) = make_int2(lo, hi);
        }
        __syncthreads();
    }

    // ---- xsq reduction ----
    xsq_red[ar * 4 + ap] = sA;
    __syncthreads();
    if (t < 256)
        xsq_l[t] = -0.5f * (xsq_red[t * 4] + xsq_red[t * 4 + 1]
                          + xsq_red[t * 4 + 2] + xsq_red[t * 4 + 3]);
    __syncthreads();

    // ---- Epilogue: exp + nontemporal store ----
#pragma unroll
    for (int c = 0; c < 2; c++) {
        const size_t mrow = m0 + wm + c * 32;
#pragma unroll
        for (int g = 0; g < 2; g++) {
            const int nc = n0 + wn + g * 32;
            const float mb = musq_l[wn + g * 32 + ln];
#pragma unroll
            for (int r = 0; r < 16; r++) {
                const int rl = (r & 3) + 8 * (r >> 2) + 4 * h;
                const float xb = xsq_l[wm + c * 32 + rl];   // LDS broadcast
                float v = __expf(acc[c][g][r] + xb + mb);
                __builtin_nontemporal_store(
                    v, out + (mrow + rl) * UNITS + nc + ln);
            }
        }
    }
}

extern "C" void kernel_launch(void* const* d_in, const int* in_sizes, int n_in,
                              void* d_out, int out_size, void* d_ws, size_t ws_size,
                              hipStream_t stream) {
    const float* inputs = (const float*)d_in[0];   // [16384, 512] fp32
    const float* mu     = (const float*)d_in[1];   // [512, 1024] fp32
    float* out = (float*)d_out;                    // [16384, 1024] fp32
    (void)d_ws; (void)ws_size;                     // no workspace needed

    rbf_fused_kernel<<<256, 1024, 0, stream>>>(inputs, mu, out);
}